// Round 1
// 1003.670 us; speedup vs baseline: 1.0921x; 1.0921x over previous
//
#include <hip/hip_runtime.h>
#include <hip/hip_bf16.h>

// Problem constants
#define NTOK 4096      // B*T
#define DDIM 1024
#define GG 4
#define EE 4
#define FF 4096
#define NEXP 16        // G*E
#define OUT_ELEMS 4194304        // N*D
#define GL_OFF 4194304           // group_logits offset in d_out (floats)
#define ENT_OFF 4210688          // entropy offset

typedef float f32x4 __attribute__((ext_vector_type(4)));
typedef short short8 __attribute__((ext_vector_type(8)));

__device__ inline unsigned short f2bf(float f) {
  unsigned int u = __float_as_uint(f);
  unsigned int rounding = 0x7FFFu + ((u >> 16) & 1u);
  return (unsigned short)((u + rounding) >> 16);
}
__device__ inline unsigned int pack2(float f0, float f1) {
  return (unsigned int)f2bf(f0) | ((unsigned int)f2bf(f1) << 16);
}
// round-half-up pack (cheaper: 5 VALU per pair vs ~10). Max err identical (0.5 ulp).
__device__ inline unsigned int pack2rn(float f0, float f1) {
  unsigned int u0 = __float_as_uint(f0), u1 = __float_as_uint(f1);
  return ((u0 + 0x8000u) >> 16) | ((u1 + 0x8000u) & 0xFFFF0000u);
}

// async global->LDS, 16B per lane. LDS dest: wave-uniform base + lane*16.
__device__ __forceinline__ void gload_lds16(const void* g, void* l) {
  __builtin_amdgcn_global_load_lds(
      (const __attribute__((address_space(1))) unsigned int*)g,
      (__attribute__((address_space(3))) unsigned int*)l, 16, 0, 0);
}

// ---------------- x -> bf16 conversion ----------------
__global__ void cvt_kernel(const float* __restrict__ x, unsigned short* __restrict__ xb) {
  int idx = blockIdx.x * 256 + threadIdx.x;   // one uint4 (8 bf16) per thread
  const float4* p = reinterpret_cast<const float4*>(x) + (size_t)idx * 2;
  float4 a = p[0], b = p[1];
  uint4 v;
  v.x = pack2(a.x, a.y); v.y = pack2(a.z, a.w);
  v.z = pack2(b.x, b.y); v.w = pack2(b.z, b.w);
  reinterpret_cast<uint4*>(xb)[idx] = v;
}

// ---------------- routing ----------------
__global__ __launch_bounds__(256) void routing_kernel(
    const float* __restrict__ x, const float* __restrict__ Wg,
    const float* __restrict__ We, float* __restrict__ out,
    int* __restrict__ cnt, int* __restrict__ tokL, int* __restrict__ hrwL,
    float* __restrict__ wslot) {
  int wave = threadIdx.x >> 6, lane = threadIdx.x & 63;
  int token = blockIdx.x * 4 + wave;
  const float4* xr = reinterpret_cast<const float4*>(x + (size_t)token * DDIM);
  float4 xv[4];
#pragma unroll
  for (int c = 0; c < 4; c++) xv[c] = xr[c * 64 + lane];

  auto dotrow = [&](const float* w) -> float {
    const float4* w4 = reinterpret_cast<const float4*>(w);
    float s = 0.f;
#pragma unroll
    for (int c = 0; c < 4; c++) {
      float4 wv = w4[c * 64 + lane];
      s += xv[c].x * wv.x + xv[c].y * wv.y + xv[c].z * wv.z + xv[c].w * wv.w;
    }
#pragma unroll
    for (int off = 32; off; off >>= 1) s += __shfl_xor(s, off, 64);
    return s;
  };

  float gl[GG];
#pragma unroll
  for (int g = 0; g < GG; g++) gl[g] = dotrow(Wg + g * DDIM);

  // top-2 groups (ties -> lower index, strict >)
  int g0 = 0;
  for (int g = 1; g < GG; g++) if (gl[g] > gl[g0]) g0 = g;
  int g1 = -1;
  for (int g = 0; g < GG; g++) { if (g == g0) continue; if (g1 < 0 || gl[g] > gl[g1]) g1 = g; }
  float e1 = __expf(gl[g1] - gl[g0]);
  float inv = 1.f / (1.f + e1);
  float w0 = inv, w1 = e1 * inv;

  // top-1 expert within each selected group
  int gsel[2] = {g0, g1};
  float wsel[2] = {w0, w1};
  int esel[2];
#pragma unroll
  for (int r = 0; r < 2; r++) {
    float el[EE];
#pragma unroll
    for (int e = 0; e < EE; e++) el[e] = dotrow(We + ((size_t)gsel[r] * EE + e) * DDIM);
    int best = 0;
    for (int e = 1; e < EE; e++) if (el[e] > el[best]) best = e;
    esel[r] = best;
  }

  // entropy of softmax over all 4 group logits
  float m = gl[0];
  for (int g = 1; g < GG; g++) m = fmaxf(m, gl[g]);
  float se = 0.f;
  for (int g = 0; g < GG; g++) se += __expf(gl[g] - m);
  float lse = __logf(se);
  float ent = 0.f;
  for (int g = 0; g < GG; g++) {
    float lp = gl[g] - m - lse;
    ent -= __expf(lp) * lp;
  }

  if (lane == 0) {
    for (int g = 0; g < GG; g++) out[GL_OFF + token * GG + g] = gl[g];
    atomicAdd(out + ENT_OFF, ent * (1.0f / NTOK));
    for (int r = 0; r < 2; r++) {
      int ge = gsel[r] * EE + esel[r];
      int pos = atomicAdd(cnt + ge, 1);
      tokL[ge * NTOK + pos] = token;
      hrwL[ge * NTOK + pos] = r * NTOK + token;
      wslot[r * NTOK + token] = wsel[r];
    }
  }
}

// ================= GEMM pass 1: H = gelu(Xg @ W1^T) =================
// 128x128 tile, BK=32, 4 waves (2x2), wave tile 64x64 (4x4 16x16 frags).
// A (bf16, gathered rows) staged via global_load_lds dwordx4.
// B (f32 weights) reg-staged with f32->bf16 convert.
__global__ __launch_bounds__(256) void up_kernel(
    const unsigned short* __restrict__ xb, const float* __restrict__ W1,
    const int* __restrict__ cnt, const int* __restrict__ tokL,
    const int* __restrict__ hrwL, unsigned short* __restrict__ H) {
  int ge = blockIdx.z, mt = blockIdx.y;
  int count = cnt[ge];
  if (mt * 128 >= count) return;
  int f0 = blockIdx.x * 128;

  __shared__ unsigned short As[128 * 32];   // [row][32] linear (m97 layout)
  __shared__ unsigned short Bs[128 * 32];
  __shared__ int rowsS[128];
  __shared__ int destS[128];

  int t = threadIdx.x;
  int w = t >> 6, lane = t & 63;
  if (t < 128) {
    int i = mt * 128 + t;
    bool valid = i < count;
    rowsS[t] = valid ? tokL[ge * NTOK + i] : 0;
    destS[t] = valid ? hrwL[ge * NTOK + i] : -1;
  }
  __syncthreads();

  // A DMA: call c covers rows c*64 + w*16 + (lane>>2), chunk (lane&3)*8 bf16
  int r0 = w * 16 + (lane >> 2);
  const unsigned short* a0 = xb + (size_t)rowsS[r0] * DDIM + (lane & 3) * 8;
  const unsigned short* a1 = xb + (size_t)rowsS[r0 + 64] * DDIM + (lane & 3) * 8;
  unsigned short* l0 = &As[w * 512];          // wave-uniform base; HW adds lane*16B
  unsigned short* l1 = &As[2048 + w * 512];

  // B stage: thread t covers weight row f0+(t>>1), 16 f32 at col (t&1)*16
  const float* bsrc = W1 + ((size_t)ge * FF + (f0 + (t >> 1))) * DDIM + (t & 1) * 16;
  unsigned short* bdst = &Bs[(t >> 1) * 32 + (t & 1) * 16];

  int m0 = (w >> 1) * 64, n0w = (w & 1) * 64;
  int kg = (lane >> 4) * 8;
  int rl = lane & 15;

  f32x4 acc[4][4] = {};

  for (int kb = 0; kb < DDIM; kb += 32) {
    gload_lds16(a0 + kb, l0);
    gload_lds16(a1 + kb, l1);
    float4 q0 = *reinterpret_cast<const float4*>(bsrc + kb);
    float4 q1 = *reinterpret_cast<const float4*>(bsrc + kb + 4);
    float4 q2 = *reinterpret_cast<const float4*>(bsrc + kb + 8);
    float4 q3 = *reinterpret_cast<const float4*>(bsrc + kb + 12);
    uint4 v0, v1;
    v0.x = pack2rn(q0.x, q0.y); v0.y = pack2rn(q0.z, q0.w);
    v0.z = pack2rn(q1.x, q1.y); v0.w = pack2rn(q1.z, q1.w);
    v1.x = pack2rn(q2.x, q2.y); v1.y = pack2rn(q2.z, q2.w);
    v1.z = pack2rn(q3.x, q3.y); v1.w = pack2rn(q3.z, q3.w);
    *reinterpret_cast<uint4*>(bdst) = v0;
    *reinterpret_cast<uint4*>(bdst + 8) = v1;
    __syncthreads();
    short8 af[4];
#pragma unroll
    for (int i = 0; i < 4; i++)
      af[i] = *reinterpret_cast<const short8*>(&As[(m0 + i * 16 + rl) * 32 + kg]);
#pragma unroll
    for (int j = 0; j < 4; j++) {
      short8 bf = *reinterpret_cast<const short8*>(&Bs[(n0w + j * 16 + rl) * 32 + kg]);
#pragma unroll
      for (int i = 0; i < 4; i++)
        acc[i][j] = __builtin_amdgcn_mfma_f32_16x16x32_bf16(af[i], bf, acc[i][j], 0, 0, 0);
    }
    __syncthreads();
  }

  int re = (lane >> 4) * 4;
#pragma unroll
  for (int i = 0; i < 4; i++) {
#pragma unroll
    for (int e = 0; e < 4; e++) {
      int hr = destS[m0 + i * 16 + re + e];
      if (hr >= 0) {
#pragma unroll
        for (int j = 0; j < 4; j++) {
          float v = acc[i][j][e];
          float gel = 0.5f * v * (1.0f + erff(v * 0.70710678118654752f));
          H[(size_t)hr * FF + f0 + n0w + j * 16 + rl] = f2bf(gel);
        }
      }
    }
  }
}

// ================= GEMM pass 2: Y = Hg @ W2^T =================
__global__ __launch_bounds__(256) void down_kernel(
    const unsigned short* __restrict__ H, const float* __restrict__ W2,
    const int* __restrict__ cnt, const int* __restrict__ hrwL,
    float* __restrict__ Y) {
  int ge = blockIdx.z, mt = blockIdx.y;
  int count = cnt[ge];
  if (mt * 128 >= count) return;
  int d0 = blockIdx.x * 128;

  __shared__ unsigned short As[128 * 32];
  __shared__ unsigned short Bs[128 * 32];
  __shared__ int rowsS[128];

  int t = threadIdx.x;
  int w = t >> 6, lane = t & 63;
  if (t < 128) {
    int i = mt * 128 + t;
    bool valid = i < count;
    rowsS[t] = valid ? hrwL[ge * NTOK + i] : -1;
  }
  __syncthreads();

  int r0 = w * 16 + (lane >> 2);
  int ar0 = rowsS[r0] < 0 ? 0 : rowsS[r0];
  int ar1 = rowsS[r0 + 64] < 0 ? 0 : rowsS[r0 + 64];
  const unsigned short* a0 = H + (size_t)ar0 * FF + (lane & 3) * 8;
  const unsigned short* a1 = H + (size_t)ar1 * FF + (lane & 3) * 8;
  unsigned short* l0 = &As[w * 512];
  unsigned short* l1 = &As[2048 + w * 512];

  const float* bsrc = W2 + ((size_t)ge * DDIM + (d0 + (t >> 1))) * FF + (t & 1) * 16;
  unsigned short* bdst = &Bs[(t >> 1) * 32 + (t & 1) * 16];

  int m0 = (w >> 1) * 64, n0w = (w & 1) * 64;
  int kg = (lane >> 4) * 8;
  int rl = lane & 15;

  f32x4 acc[4][4] = {};

  for (int kb = 0; kb < FF; kb += 32) {
    gload_lds16(a0 + kb, l0);
    gload_lds16(a1 + kb, l1);
    float4 q0 = *reinterpret_cast<const float4*>(bsrc + kb);
    float4 q1 = *reinterpret_cast<const float4*>(bsrc + kb + 4);
    float4 q2 = *reinterpret_cast<const float4*>(bsrc + kb + 8);
    float4 q3 = *reinterpret_cast<const float4*>(bsrc + kb + 12);
    uint4 v0, v1;
    v0.x = pack2rn(q0.x, q0.y); v0.y = pack2rn(q0.z, q0.w);
    v0.z = pack2rn(q1.x, q1.y); v0.w = pack2rn(q1.z, q1.w);
    v1.x = pack2rn(q2.x, q2.y); v1.y = pack2rn(q2.z, q2.w);
    v1.z = pack2rn(q3.x, q3.y); v1.w = pack2rn(q3.z, q3.w);
    *reinterpret_cast<uint4*>(bdst) = v0;
    *reinterpret_cast<uint4*>(bdst + 8) = v1;
    __syncthreads();
    short8 af[4];
#pragma unroll
    for (int i = 0; i < 4; i++)
      af[i] = *reinterpret_cast<const short8*>(&As[(m0 + i * 16 + rl) * 32 + kg]);
#pragma unroll
    for (int j = 0; j < 4; j++) {
      short8 bf = *reinterpret_cast<const short8*>(&Bs[(n0w + j * 16 + rl) * 32 + kg]);
#pragma unroll
      for (int i = 0; i < 4; i++)
        acc[i][j] = __builtin_amdgcn_mfma_f32_16x16x32_bf16(af[i], bf, acc[i][j], 0, 0, 0);
    }
    __syncthreads();
  }

  int re = (lane >> 4) * 4;
#pragma unroll
  for (int i = 0; i < 4; i++) {
#pragma unroll
    for (int e = 0; e < 4; e++) {
      int hr = rowsS[m0 + i * 16 + re + e];
      if (hr >= 0) {
#pragma unroll
        for (int j = 0; j < 4; j++) {
          Y[(size_t)hr * DDIM + d0 + n0w + j * 16 + rl] = acc[i][j][e];
        }
      }
    }
  }
}

// ---------------- combine: out = w0*Y0 + w1*Y1 ----------------
__global__ void combine_kernel(const float* __restrict__ Y,
                               const float* __restrict__ wslot,
                               float* __restrict__ out) {
  int idx = blockIdx.x * 256 + threadIdx.x;    // one float4 per thread
  int token = idx >> 8;                        // 256 float4 per row
  float w0 = wslot[token], w1 = wslot[NTOK + token];
  float4 a = reinterpret_cast<const float4*>(Y)[idx];
  float4 b = reinterpret_cast<const float4*>(Y + (size_t)NTOK * DDIM)[idx];
  float4 o;
  o.x = w0 * a.x + w1 * b.x;
  o.y = w0 * a.y + w1 * b.y;
  o.z = w0 * a.z + w1 * b.z;
  o.w = w0 * a.w + w1 * b.w;
  reinterpret_cast<float4*>(out)[idx] = o;
}

extern "C" void kernel_launch(void* const* d_in, const int* in_sizes, int n_in,
                              void* d_out, int out_size, void* d_ws, size_t ws_size,
                              hipStream_t stream) {
  const float* x  = (const float*)d_in[0];
  const float* Wg = (const float*)d_in[1];
  const float* We = (const float*)d_in[2];
  const float* W1 = (const float*)d_in[3];
  const float* W2 = (const float*)d_in[4];
  float* out = (float*)d_out;
  char* ws = (char*)d_ws;

  // workspace layout
  int* cnt = (int*)(ws);                               // 64 B (zeroed)
  int* tokL = (int*)(ws + 1024);                       // 16*4096*4
  int* hrwL = (int*)(ws + 1024 + 262144);              // 16*4096*4
  float* wslot = (float*)(ws + 1024 + 524288);         // 2*4096*4
  unsigned short* xb = (unsigned short*)(ws + (1 << 20));            // 8 MB
  unsigned short* H  = (unsigned short*)(ws + (1 << 20) + 8388608);  // 67 MB
  float* Y = (float*)(ws + (1 << 20) + 8388608 + 67108864);          // 33.5 MB

  hipMemsetAsync(d_out, 0, (size_t)out_size * sizeof(float), stream);
  hipMemsetAsync(ws, 0, 1024, stream);

  cvt_kernel<<<2048, 256, 0, stream>>>(x, xb);
  routing_kernel<<<1024, 256, 0, stream>>>(x, Wg, We, out, cnt, tokL, hrwL, wslot);
  up_kernel<<<dim3(FF / 128, 32, NEXP), 256, 0, stream>>>(xb, W1, cnt, tokL, hrwL, H);
  down_kernel<<<dim3(DDIM / 128, 32, NEXP), 256, 0, stream>>>(H, W2, cnt, hrwL, Y);
  combine_kernel<<<4096, 256, 0, stream>>>(Y, wslot, out);
}

// Round 2
// 915.890 us; speedup vs baseline: 1.1967x; 1.0958x over previous
//
#include <hip/hip_runtime.h>
#include <hip/hip_bf16.h>

// Problem constants
#define NTOK 4096      // B*T
#define DDIM 1024
#define GG 4
#define EE 4
#define FF 4096
#define NEXP 16        // G*E
#define OUT_ELEMS 4194304        // N*D
#define GL_OFF 4194304           // group_logits offset in d_out (floats)
#define ENT_OFF 4210688          // entropy offset

typedef float f32x4 __attribute__((ext_vector_type(4)));
typedef short short8 __attribute__((ext_vector_type(8)));

__device__ inline unsigned short f2bf(float f) {
  unsigned int u = __float_as_uint(f);
  unsigned int rounding = 0x7FFFu + ((u >> 16) & 1u);
  return (unsigned short)((u + rounding) >> 16);
}
__device__ inline unsigned int pack2(float f0, float f1) {
  return (unsigned int)f2bf(f0) | ((unsigned int)f2bf(f1) << 16);
}
// round-half-up pack (cheaper). Max err identical (0.5 ulp).
__device__ inline unsigned int pack2rn(float f0, float f1) {
  unsigned int u0 = __float_as_uint(f0), u1 = __float_as_uint(f1);
  return ((u0 + 0x8000u) >> 16) | ((u1 + 0x8000u) & 0xFFFF0000u);
}

// async global->LDS, 16B per lane. LDS dest: wave-uniform base + lane*16.
__device__ __forceinline__ void gload_lds16(const void* g, void* l) {
  __builtin_amdgcn_global_load_lds(
      (const __attribute__((address_space(1))) unsigned int*)g,
      (__attribute__((address_space(3))) unsigned int*)l, 16, 0, 0);
}

// ---------------- x -> bf16 conversion ----------------
__global__ void cvt_kernel(const float* __restrict__ x, unsigned short* __restrict__ xb) {
  int idx = blockIdx.x * 256 + threadIdx.x;   // one uint4 (8 bf16) per thread
  const float4* p = reinterpret_cast<const float4*>(x) + (size_t)idx * 2;
  float4 a = p[0], b = p[1];
  uint4 v;
  v.x = pack2(a.x, a.y); v.y = pack2(a.z, a.w);
  v.z = pack2(b.x, b.y); v.w = pack2(b.z, b.w);
  reinterpret_cast<uint4*>(xb)[idx] = v;
}

// ---------------- routing ----------------
__global__ __launch_bounds__(256) void routing_kernel(
    const float* __restrict__ x, const float* __restrict__ Wg,
    const float* __restrict__ We, float* __restrict__ out,
    int* __restrict__ cnt, int* __restrict__ tokL, int* __restrict__ hrwL,
    float* __restrict__ wslot) {
  int wave = threadIdx.x >> 6, lane = threadIdx.x & 63;
  int token = blockIdx.x * 4 + wave;
  const float4* xr = reinterpret_cast<const float4*>(x + (size_t)token * DDIM);
  float4 xv[4];
#pragma unroll
  for (int c = 0; c < 4; c++) xv[c] = xr[c * 64 + lane];

  auto dotrow = [&](const float* w) -> float {
    const float4* w4 = reinterpret_cast<const float4*>(w);
    float s = 0.f;
#pragma unroll
    for (int c = 0; c < 4; c++) {
      float4 wv = w4[c * 64 + lane];
      s += xv[c].x * wv.x + xv[c].y * wv.y + xv[c].z * wv.z + xv[c].w * wv.w;
    }
#pragma unroll
    for (int off = 32; off; off >>= 1) s += __shfl_xor(s, off, 64);
    return s;
  };

  float gl[GG];
#pragma unroll
  for (int g = 0; g < GG; g++) gl[g] = dotrow(Wg + g * DDIM);

  // top-2 groups (ties -> lower index, strict >)
  int g0 = 0;
  for (int g = 1; g < GG; g++) if (gl[g] > gl[g0]) g0 = g;
  int g1 = -1;
  for (int g = 0; g < GG; g++) { if (g == g0) continue; if (g1 < 0 || gl[g] > gl[g1]) g1 = g; }
  float e1 = __expf(gl[g1] - gl[g0]);
  float inv = 1.f / (1.f + e1);
  float w0 = inv, w1 = e1 * inv;

  // top-1 expert within each selected group
  int gsel[2] = {g0, g1};
  float wsel[2] = {w0, w1};
  int esel[2];
#pragma unroll
  for (int r = 0; r < 2; r++) {
    float el[EE];
#pragma unroll
    for (int e = 0; e < EE; e++) el[e] = dotrow(We + ((size_t)gsel[r] * EE + e) * DDIM);
    int best = 0;
    for (int e = 1; e < EE; e++) if (el[e] > el[best]) best = e;
    esel[r] = best;
  }

  // entropy of softmax over all 4 group logits
  float m = gl[0];
  for (int g = 1; g < GG; g++) m = fmaxf(m, gl[g]);
  float se = 0.f;
  for (int g = 0; g < GG; g++) se += __expf(gl[g] - m);
  float lse = __logf(se);
  float ent = 0.f;
  for (int g = 0; g < GG; g++) {
    float lp = gl[g] - m - lse;
    ent -= __expf(lp) * lp;
  }

  if (lane == 0) {
    for (int g = 0; g < GG; g++) out[GL_OFF + token * GG + g] = gl[g];
    atomicAdd(out + ENT_OFF, ent * (1.0f / NTOK));
    for (int r = 0; r < 2; r++) {
      int ge = gsel[r] * EE + esel[r];
      int pos = atomicAdd(cnt + ge, 1);
      tokL[ge * NTOK + pos] = token;
      hrwL[ge * NTOK + pos] = r * NTOK + token;
      wslot[r * NTOK + token] = wsel[r];
    }
  }
}

// ================= expert GEMM (2-phase pipelined, BK=64, swizzled LDS) ====
// Tile 128(M tokens) x 128(N) x 64(K). 512 threads = 8 waves (4 wave-rows x
// 2 wave-cols), wave tile 32x64 -> acc[2][4] 16x16 frags, 16 MFMA/wave/iter.
// A (bf16 gathered rows) -> LDS via global_load_lds with PRE-SWIZZLED global
// source (linear LDS dest, rule #21). B (f32 weights) -> regs -> pack bf16 ->
// swizzled ds_write. Swizzle: phys_chunk = logical_chunk ^ (row & 7), chunks
// are 16B. Stage t+1 before compute of t; single barrier per K-tile so the
// vmcnt drain lands AFTER the MFMAs (T3-minimum 2-phase).
template <int KDIM, bool UP>
__global__ __launch_bounds__(512, 4) void moe_gemm(
    const unsigned short* __restrict__ A, const float* __restrict__ W,
    const int* __restrict__ cnt, const int* __restrict__ tokL,
    const int* __restrict__ hrwL, unsigned short* __restrict__ Hout,
    float* __restrict__ Yout) {
  constexpr int NT = KDIM / 64;
  constexpr int NROWS = UP ? FF : DDIM;
  int ge = blockIdx.z, mt = blockIdx.y;
  int count = cnt[ge];
  if (mt * 128 >= count) return;
  int n0 = blockIdx.x * 128;

  __shared__ alignas(16) unsigned short As[2][128 * 64];
  __shared__ alignas(16) unsigned short Bs[2][128 * 64];
  __shared__ int srcS[128];
  __shared__ int dstS[128];

  int t = threadIdx.x;
  int w = t >> 6, lane = t & 63;
  if (t < 128) {
    int i = mt * 128 + t;
    bool valid = i < count;
    int hrw = valid ? hrwL[ge * NTOK + i] : -1;
    dstS[t] = hrw;
    if (UP) srcS[t] = valid ? tokL[ge * NTOK + i] : 0;
    else    srcS[t] = hrw < 0 ? 0 : hrw;
  }
  __syncthreads();

  // ---- A staging addresses (2 gload_lds calls per wave per tile) ----
  int rA = w * 16 + (lane >> 3);              // rows rA (call 0), rA+8 (call 1)
  int cA = (lane & 7) ^ (lane >> 3);          // pre-swizzled source chunk
  const unsigned short* gA0 = A + (size_t)srcS[rA] * KDIM + cA * 8;
  const unsigned short* gA1 = A + (size_t)srcS[rA + 8] * KDIM + cA * 8;

  // ---- B staging addresses (rows rB and rB+64, chunk cB) ----
  int rB = t >> 3;                             // 0..63
  int cB = t & 7;
  const float* gB0 = W + ((size_t)ge * NROWS + n0 + rB) * KDIM + cB * 8;
  const float* gB1 = W + ((size_t)ge * NROWS + n0 + 64 + rB) * KDIM + cB * 8;
  int pB = (cB ^ (rB & 7)) * 8;                // phys chunk offset (shorts)

  // ---- compute-side indices ----
  int wr = w >> 1, wc = w & 1;
  int m0 = wr * 32, nw = wc * 64;
  int rl = lane & 15, kq = lane >> 4;
  int xr = rl & 7;

  f32x4 acc[2][4] = {};
  int cur = 0;

  // prologue: stage tile 0 into buffer 0
  {
    gload_lds16(gA0, &As[0][(w * 16) * 64]);
    gload_lds16(gA1, &As[0][(w * 16 + 8) * 64]);
    float4 q0 = *reinterpret_cast<const float4*>(gB0);
    float4 q1 = *reinterpret_cast<const float4*>(gB0 + 4);
    float4 q2 = *reinterpret_cast<const float4*>(gB1);
    float4 q3 = *reinterpret_cast<const float4*>(gB1 + 4);
    uint4 v0, v1;
    v0.x = pack2rn(q0.x, q0.y); v0.y = pack2rn(q0.z, q0.w);
    v0.z = pack2rn(q1.x, q1.y); v0.w = pack2rn(q1.z, q1.w);
    v1.x = pack2rn(q2.x, q2.y); v1.y = pack2rn(q2.z, q2.w);
    v1.z = pack2rn(q3.x, q3.y); v1.w = pack2rn(q3.z, q3.w);
    *reinterpret_cast<uint4*>(&Bs[0][rB * 64 + pB]) = v0;
    *reinterpret_cast<uint4*>(&Bs[0][(rB + 64) * 64 + pB]) = v1;
  }
  __syncthreads();

  for (int it = 0; it < NT; ++it) {
    int kb = (it + 1) * 64;
    bool pre = (it + 1) < NT;
    float4 q0, q1, q2, q3;
    if (pre) {
      // issue next-tile loads BEFORE compute (latency hides under MFMAs)
      gload_lds16(gA0 + kb, &As[cur ^ 1][(w * 16) * 64]);
      gload_lds16(gA1 + kb, &As[cur ^ 1][(w * 16 + 8) * 64]);
      q0 = *reinterpret_cast<const float4*>(gB0 + kb);
      q1 = *reinterpret_cast<const float4*>(gB0 + kb + 4);
      q2 = *reinterpret_cast<const float4*>(gB1 + kb);
      q3 = *reinterpret_cast<const float4*>(gB1 + kb + 4);
    }
    // compute current tile
    const unsigned short* Ab = As[cur];
    const unsigned short* Bb = Bs[cur];
#pragma unroll
    for (int kk = 0; kk < 2; kk++) {
      int cph = ((kk * 4 + kq) ^ xr) * 8;      // swizzled chunk offset
      short8 af0 = *reinterpret_cast<const short8*>(&Ab[(m0 + rl) * 64 + cph]);
      short8 af1 = *reinterpret_cast<const short8*>(&Ab[(m0 + 16 + rl) * 64 + cph]);
#pragma unroll
      for (int j = 0; j < 4; j++) {
        short8 bf = *reinterpret_cast<const short8*>(&Bb[(nw + j * 16 + rl) * 64 + cph]);
        acc[0][j] = __builtin_amdgcn_mfma_f32_16x16x32_bf16(af0, bf, acc[0][j], 0, 0, 0);
        acc[1][j] = __builtin_amdgcn_mfma_f32_16x16x32_bf16(af1, bf, acc[1][j], 0, 0, 0);
      }
    }
    if (pre) {
      uint4 v0, v1;
      v0.x = pack2rn(q0.x, q0.y); v0.y = pack2rn(q0.z, q0.w);
      v0.z = pack2rn(q1.x, q1.y); v0.w = pack2rn(q1.z, q1.w);
      v1.x = pack2rn(q2.x, q2.y); v1.y = pack2rn(q2.z, q2.w);
      v1.z = pack2rn(q3.x, q3.y); v1.w = pack2rn(q3.z, q3.w);
      *reinterpret_cast<uint4*>(&Bs[cur ^ 1][rB * 64 + pB]) = v0;
      *reinterpret_cast<uint4*>(&Bs[cur ^ 1][(rB + 64) * 64 + pB]) = v1;
    }
    __syncthreads();   // drains gload_lds (vmcnt) + ds ops once per K-tile
    cur ^= 1;
  }

  // epilogue
  int re = kq * 4;
#pragma unroll
  for (int i = 0; i < 2; i++) {
#pragma unroll
    for (int e = 0; e < 4; e++) {
      int hr = dstS[m0 + i * 16 + re + e];
      if (hr >= 0) {
        if constexpr (UP) {
#pragma unroll
          for (int j = 0; j < 4; j++) {
            float v = acc[i][j][e];
            float gel = 0.5f * v * (1.0f + erff(v * 0.70710678118654752f));
            Hout[(size_t)hr * FF + n0 + nw + j * 16 + rl] = f2bf(gel);
          }
        } else {
#pragma unroll
          for (int j = 0; j < 4; j++)
            Yout[(size_t)hr * DDIM + n0 + nw + j * 16 + rl] = acc[i][j][e];
        }
      }
    }
  }
}

// ---------------- combine: out = w0*Y0 + w1*Y1 ----------------
__global__ void combine_kernel(const float* __restrict__ Y,
                               const float* __restrict__ wslot,
                               float* __restrict__ out) {
  int idx = blockIdx.x * 256 + threadIdx.x;    // one float4 per thread
  int token = idx >> 8;                        // 256 float4 per row
  float w0 = wslot[token], w1 = wslot[NTOK + token];
  float4 a = reinterpret_cast<const float4*>(Y)[idx];
  float4 b = reinterpret_cast<const float4*>(Y + (size_t)NTOK * DDIM)[idx];
  float4 o;
  o.x = w0 * a.x + w1 * b.x;
  o.y = w0 * a.y + w1 * b.y;
  o.z = w0 * a.z + w1 * b.z;
  o.w = w0 * a.w + w1 * b.w;
  reinterpret_cast<float4*>(out)[idx] = o;
}

extern "C" void kernel_launch(void* const* d_in, const int* in_sizes, int n_in,
                              void* d_out, int out_size, void* d_ws, size_t ws_size,
                              hipStream_t stream) {
  const float* x  = (const float*)d_in[0];
  const float* Wg = (const float*)d_in[1];
  const float* We = (const float*)d_in[2];
  const float* W1 = (const float*)d_in[3];
  const float* W2 = (const float*)d_in[4];
  float* out = (float*)d_out;
  char* ws = (char*)d_ws;

  // workspace layout
  int* cnt = (int*)(ws);                               // 64 B (zeroed)
  int* tokL = (int*)(ws + 1024);                       // 16*4096*4
  int* hrwL = (int*)(ws + 1024 + 262144);              // 16*4096*4
  float* wslot = (float*)(ws + 1024 + 524288);         // 2*4096*4
  unsigned short* xb = (unsigned short*)(ws + (1 << 20));            // 8 MB
  unsigned short* H  = (unsigned short*)(ws + (1 << 20) + 8388608);  // 67 MB
  float* Y = (float*)(ws + (1 << 20) + 8388608 + 67108864);          // 33.5 MB

  hipMemsetAsync(d_out, 0, (size_t)out_size * sizeof(float), stream);
  hipMemsetAsync(ws, 0, 1024, stream);

  cvt_kernel<<<2048, 256, 0, stream>>>(x, xb);
  routing_kernel<<<1024, 256, 0, stream>>>(x, Wg, We, out, cnt, tokL, hrwL, wslot);
  moe_gemm<DDIM, true><<<dim3(FF / 128, 32, NEXP), 512, 0, stream>>>(
      xb, W1, cnt, tokL, hrwL, H, nullptr);
  moe_gemm<FF, false><<<dim3(DDIM / 128, 32, NEXP), 512, 0, stream>>>(
      H, W2, cnt, tokL, hrwL, nullptr, Y);
  combine_kernel<<<4096, 256, 0, stream>>>(Y, wslot, out);
}